// Round 10
// baseline (2450.584 us; speedup 1.0000x reference)
//
#include <hip/hip_runtime.h>
#include <hip/hip_bf16.h>

// LSTM B=64, T=256, ID=512, HD=1024. Gates F,I,A,O.
// Round 14: arrival-driven chunked consumption. r13 falsified the volume
// theory (h volume halved -> only -5%): the floor is the SERIAL CHAIN
// amplified by the global barrier -- every block waits for the straggler
// before doing ANY of its ~3000cy of work. K-accumulation order is free,
// so consume in 4 groups (8 kk slices = 16 source blocks each), each gated
// only by its OWN 16 flags: straggler wait overlaps the ready groups'
// loads+MFMAs; only the last group's tail stays exposed.
//  - vmcnt poison avoidance: a compute-wave flag poll would need vmcnt(0),
//    draining its h loads. vmcnt is PER-WAVE -> 5th wave (block=320) polls
//    all 64 flags (one coalesced 256B load + __ballot), relays per-group
//    readiness through LDS ready[4]; compute waves spin on LDS (lgkmcnt
//    only, h-load pipeline untouched).
//  - consumer barrier deleted (replaced by spins); producer publish barrier
//    kept: 255 s_barriers on both wave paths, wave4 exits after last poll.
//  - 2-step buffer safety unchanged: flags >= t+2 from ALL blocks implies
//    all step-t+1 reads finished (publish follows reads).
// Everything else as r13 (UPB=16 gate-local activations, 128KB LDS Wh,
// issue8 "=&v", counted vmcnt(8), block flag after drain+barrier).

#define B_  64
#define T_  256
#define ID_ 512
#define HD_ 1024
#define NG_ 4096
#define M1_ (B_ * T_)
#define NBLK 64
#define UPB  16

typedef __bf16 bf16x8 __attribute__((ext_vector_type(8)));
typedef float  f32x4  __attribute__((ext_vector_type(4)));
typedef int    i32x4  __attribute__((ext_vector_type(4)));
typedef short  s16x4  __attribute__((ext_vector_type(4)));

using bf16 = __hip_bfloat16;

__device__ __forceinline__ float sigmoid_fast(float x) {
    return 1.0f / (1.0f + __expf(-x));
}
__device__ __forceinline__ float tanh_fast(float x) {
    return 1.0f - 2.0f / (__expf(2.0f * x) + 1.0f);
}
__device__ __forceinline__ unsigned short bf16_bits(float x) {
    union { bf16 h; unsigned short u; } cv;
    cv.h = __float2bfloat16(x);
    return cv.u;
}
__device__ __forceinline__ bf16x8 as_bf16x8(i32x4 v) {
    union { i32x4 i; bf16x8 h; } cv;
    cv.i = v;
    return cv.h;
}

// 8 coherent 16-B loads from one base (offsets 0..448 B), one asm block.
// "=&v" EARLY-CLOBBER is load-bearing: outputs must not alias the address
// pair (loads 2-8 read %8 after load 1's data can return).
__device__ __forceinline__ void issue8(i32x4* dst, const bf16* gbase) {
    asm volatile(
        "global_load_dwordx4 %0, %8, off sc0 sc1\n\t"
        "global_load_dwordx4 %1, %8, off offset:64 sc0 sc1\n\t"
        "global_load_dwordx4 %2, %8, off offset:128 sc0 sc1\n\t"
        "global_load_dwordx4 %3, %8, off offset:192 sc0 sc1\n\t"
        "global_load_dwordx4 %4, %8, off offset:256 sc0 sc1\n\t"
        "global_load_dwordx4 %5, %8, off offset:320 sc0 sc1\n\t"
        "global_load_dwordx4 %6, %8, off offset:384 sc0 sc1\n\t"
        "global_load_dwordx4 %7, %8, off offset:448 sc0 sc1"
        : "=&v"(dst[0]), "=&v"(dst[1]), "=&v"(dst[2]), "=&v"(dst[3]),
          "=&v"(dst[4]), "=&v"(dst[5]), "=&v"(dst[6]), "=&v"(dst[7])
        : "v"(gbase));
}

// ---------------------------------------------------------------- prep ----
__global__ __launch_bounds__(256) void prep_kernel(
    const float* __restrict__ x, const float* __restrict__ Wi,
    const float* __restrict__ Wh, bf16* __restrict__ xb,
    bf16* __restrict__ wiT, bf16* __restrict__ whT,
    bf16* __restrict__ hbuf, int* __restrict__ flags) {
    const int tid = blockIdx.x * 256 + threadIdx.x;  // [0, 2097152)

    if (tid < NBLK * 4 * 16) flags[tid] = 0;          // covers 64 block flags
    if (tid < (B_ * HD_) / 4)                         // h[-1] = 0 (buf0)
        *reinterpret_cast<s16x4*>(hbuf + (size_t)tid * 4) = s16x4{0, 0, 0, 0};

    const float4 v = reinterpret_cast<const float4*>(x)[tid];
    bf16 tmp[4] = { __float2bfloat16(v.x), __float2bfloat16(v.y),
                    __float2bfloat16(v.z), __float2bfloat16(v.w) };
    *reinterpret_cast<s16x4*>(xb + 4 * (size_t)tid) =
        *reinterpret_cast<s16x4*>(tmp);

    {   // WiT[n][k] = Wi[k][n]
        const int n = tid >> 9, k = tid & 511;
        wiT[tid] = __float2bfloat16(Wi[(size_t)k * NG_ + n]);
    }
    for (int e = 0; e < 2; ++e) {  // WhT[n][k] = Wh[k][n]
        const int idx = 2 * tid + e;
        const int n = idx >> 10, k = idx & 1023;
        whT[idx] = __float2bfloat16(Wh[(size_t)k * NG_ + n]);
    }
}

// ---------------------------------------------------- phase-1 gates GEMM ----
// gates3 layout: [t][blk(64)][tid(256)][16] bf16, e = gate*4 + (unit&3),
// tid2 = (b>>4)*64 + (unit>>2)*16 + (b&15)  -- step-MFMA acc order (UPB=16).
__global__ __launch_bounds__(256) void gates_gemm_kernel(
    const bf16* __restrict__ xb, const bf16* __restrict__ wiT,
    const float* __restrict__ bi, const float* __restrict__ bh,
    bf16* __restrict__ gates3) {
    __shared__ __align__(16) bf16 As[128 * 40];
    __shared__ __align__(16) bf16 Bs[128 * 40];
    const int tid  = threadIdx.x;
    const int lane = tid & 63, wave = tid >> 6;
    const int wm = wave >> 1, wn = wave & 1;
    const int l15 = lane & 15, quad = lane >> 4;
    const int row0 = blockIdx.x * 128, col0 = blockIdx.y * 128;

    f32x4 acc[4][4];
    for (int i = 0; i < 4; ++i)
        for (int j = 0; j < 4; ++j) acc[i][j] = f32x4{0.f, 0.f, 0.f, 0.f};

    for (int kt = 0; kt < ID_ / 32; ++kt) {
        const int k0 = kt * 32;
        for (int L = tid; L < 512; L += 256) {
            const int r = L >> 2, s = L & 3;
            *reinterpret_cast<i32x4*>(&As[r * 40 + s * 8]) =
                *reinterpret_cast<const i32x4*>(xb + (size_t)(row0 + r) * ID_ + k0 + s * 8);
            *reinterpret_cast<i32x4*>(&Bs[r * 40 + s * 8]) =
                *reinterpret_cast<const i32x4*>(wiT + (size_t)(col0 + r) * ID_ + k0 + s * 8);
        }
        __syncthreads();
        bf16x8 af[4], bfv[4];
        for (int mt = 0; mt < 4; ++mt)
            af[mt] = *reinterpret_cast<const bf16x8*>(
                &As[(wm * 64 + mt * 16 + l15) * 40 + quad * 8]);
        for (int nt = 0; nt < 4; ++nt)
            bfv[nt] = *reinterpret_cast<const bf16x8*>(
                &Bs[(wn * 64 + nt * 16 + l15) * 40 + quad * 8]);
        for (int mt = 0; mt < 4; ++mt)
            for (int nt = 0; nt < 4; ++nt)
                acc[mt][nt] = __builtin_amdgcn_mfma_f32_16x16x32_bf16(
                    af[mt], bfv[nt], acc[mt][nt], 0, 0, 0);
        __syncthreads();
    }
    // epilogue: +(bi+bh), store to gates3 in persistent-kernel acc order
    for (int mt = 0; mt < 4; ++mt) {
        for (int nt = 0; nt < 4; ++nt) {
            const int cg = col0 + wn * 64 + nt * 16 + l15;
            const int g = cg >> 10, u = cg & 1023;      // gate, hidden unit
            const int blk = u >> 4, ul = u & 15;
            const int q2 = ul >> 2, r2 = ul & 3;
            const int e = g * 4 + r2;
            const float bias = bi[cg] + bh[cg];
            for (int r = 0; r < 4; ++r) {
                const int rg = row0 + wm * 64 + mt * 16 + quad * 4 + r;
                const int b = rg >> 8, t = rg & 255;    // row = b*T + t
                const int tid2 = (b >> 4) * 64 + q2 * 16 + (b & 15);
                gates3[(((size_t)t * NBLK + blk) * 256 + tid2) * 16 + e] =
                    __float2bfloat16(acc[mt][nt][r] + bias);
            }
        }
    }
}

// ------------------------------------------------- persistent LSTM steps ----
// 320 threads: waves 0-3 compute, wave 4 = flag poller (LDS relay).
// LDS Wh tile: 64 m-rows (4 gates x 16 units) x 1024 k, 128 KB.
// Element layout: kk*2048 + sel*512 + lane*8 (sel = gate).
__global__ __launch_bounds__(320, 1) void lstm_persistent_kernel(
    const bf16* __restrict__ gates3, const bf16* __restrict__ whT,
    bf16* __restrict__ hbuf, float* __restrict__ out, int* __restrict__ flags) {
    __shared__ __align__(16) bf16 whs[32 * 4 * 64 * 8];   // 128 KB
    __shared__ int ready[4];                              // per-group gate
    const int tid  = threadIdx.x;
    const int lane = tid & 63, w = tid >> 6;
    const int l15 = lane & 15, quad = lane >> 4;
    const int blk = blockIdx.x;                 // units [blk*16, blk*16+16)

    if (tid < 4) ready[tid] = 0;
    // ---- stage Wh A-tile into LDS (once), linear 16B writes ----
    for (int c = tid; c < 8192; c += 320) {
        const int kk = c >> 8, sel = (c >> 6) & 3, ln = c & 63;
        const size_t wrow = (size_t)(sel * HD_ + blk * UPB + (ln & 15));
        const int col = (ln >> 4) * 8 + kk * 32;
        *reinterpret_cast<i32x4*>(whs + (size_t)c * 8) =
            *reinterpret_cast<const i32x4*>(whT + wrow * HD_ + col);
    }
    __syncthreads();

    // ================= wave 4: dedicated flag poller =================
    // Polls flags[0..63] (one coalesced 256B load), ballots, and relays
    // per-group readiness (group g = source blocks 16g..16g+15) to LDS.
    // Own vmcnt -- compute waves' h-load pipelines stay clean.
    if (w == 4) {
        const volatile int* fp = (const volatile int*)(flags + lane);
        for (int t2 = 1; t2 < T_; ++t2) {
            asm volatile("s_barrier" ::: "memory");   // pairs with publish
            for (;;) {
                const int f = *fp;
                const unsigned long long m = __ballot(f >= t2);
                if (lane < 4 &&
                    (((m >> (lane * 16)) & 0xFFFFull) == 0xFFFFull))
                    ((volatile int*)ready)[lane] = t2;
                if (m == ~0ull) break;
            }
        }
        return;   // all 255 barriers consumed; no barrier at t = T-1
    }

    // ================= waves 0-3: compute =================
    const bf16* wb = whs + (size_t)lane * 8;    // + kk*2048 + sel*512
    const int b = w * 16 + l15;                 // batch row
    float cs[4] = {0.f, 0.f, 0.f, 0.f};

    // gx double-buffer (16 gates: F r0-3, I r0-3 | A, O)
    size_t gb0 = ((size_t)blk * 256 + tid) * 16;
    bf16x8 gxa_n = *reinterpret_cast<const bf16x8*>(gates3 + gb0);
    bf16x8 gxb_n = *reinterpret_cast<const bf16x8*>(gates3 + gb0 + 8);

    for (int t = 0; t < T_; ++t) {
        const bf16* hin  = hbuf + (size_t)(t & 1) * (B_ * HD_);
        bf16*       hout = hbuf + (size_t)((t + 1) & 1) * (B_ * HD_);
        const bf16x8 gxa = gxa_n, gxb = gxb_n;

        f32x4 aFe{0.f,0.f,0.f,0.f}, aFo{0.f,0.f,0.f,0.f};
        f32x4 aIe{0.f,0.f,0.f,0.f}, aIo{0.f,0.f,0.f,0.f};
        f32x4 aAe{0.f,0.f,0.f,0.f}, aAo{0.f,0.f,0.f,0.f};
        f32x4 aOe{0.f,0.f,0.f,0.f}, aOo{0.f,0.f,0.f,0.f};

        const bf16* hb_base = hin + (size_t)b * HD_ + quad * 8;
        i32x4 hbA[8], hbB[8];

        auto spin = [&](int g) {
            const volatile int* r = (const volatile int*)&ready[g];
            while (*r < t) {}
            __asm__ __volatile__("" ::: "memory");
        };
        auto consume8 = [&](const i32x4* hbg, const int kkb) {
#pragma unroll
            for (int i = 0; i < 8; i += 2) {
                const int kk = kkb + i;
                const bf16* f0 = wb + (size_t)kk * 2048;
                const bf16* f1 = f0 + 2048;
                const bf16x8 he = as_bf16x8(hbg[i]);
                const bf16x8 ho = as_bf16x8(hbg[i + 1]);
                aFe = __builtin_amdgcn_mfma_f32_16x16x32_bf16(
                    *reinterpret_cast<const bf16x8*>(f0),        he, aFe, 0, 0, 0);
                aIe = __builtin_amdgcn_mfma_f32_16x16x32_bf16(
                    *reinterpret_cast<const bf16x8*>(f0 + 512),  he, aIe, 0, 0, 0);
                aAe = __builtin_amdgcn_mfma_f32_16x16x32_bf16(
                    *reinterpret_cast<const bf16x8*>(f0 + 1024), he, aAe, 0, 0, 0);
                aOe = __builtin_amdgcn_mfma_f32_16x16x32_bf16(
                    *reinterpret_cast<const bf16x8*>(f0 + 1536), he, aOe, 0, 0, 0);
                aFo = __builtin_amdgcn_mfma_f32_16x16x32_bf16(
                    *reinterpret_cast<const bf16x8*>(f1),        ho, aFo, 0, 0, 0);
                aIo = __builtin_amdgcn_mfma_f32_16x16x32_bf16(
                    *reinterpret_cast<const bf16x8*>(f1 + 512),  ho, aIo, 0, 0, 0);
                aAo = __builtin_amdgcn_mfma_f32_16x16x32_bf16(
                    *reinterpret_cast<const bf16x8*>(f1 + 1024), ho, aAo, 0, 0, 0);
                aOo = __builtin_amdgcn_mfma_f32_16x16x32_bf16(
                    *reinterpret_cast<const bf16x8*>(f1 + 1536), ho, aOo, 0, 0, 0);
            }
        };

        // ---- arrival-gated, 2-deep pipelined consumption ----
        if (t > 0) spin(0);
        issue8(hbA, hb_base);             // kk  0..7  (blocks  0..15)
        if (t > 0) spin(1);
        issue8(hbB, hb_base + 8 * 32);    // kk  8..15 (blocks 16..31)
        asm volatile("s_waitcnt vmcnt(8)" ::: "memory");
        __builtin_amdgcn_sched_barrier(0);
        consume8(hbA, 0);
        if (t > 0) spin(2);
        issue8(hbA, hb_base + 16 * 32);   // kk 16..23 (blocks 32..47)
        asm volatile("s_waitcnt vmcnt(8)" ::: "memory");
        __builtin_amdgcn_sched_barrier(0);
        consume8(hbB, 8);
        if (t > 0) spin(3);
        issue8(hbB, hb_base + 24 * 32);   // kk 24..31 (blocks 48..63)
        asm volatile("s_waitcnt vmcnt(8)" ::: "memory");
        __builtin_amdgcn_sched_barrier(0);
        consume8(hbA, 16);
        asm volatile("s_waitcnt vmcnt(0)" ::: "memory");
        __builtin_amdgcn_sched_barrier(0);
        consume8(hbB, 24);

        // ---- activations: all 4 gates for (unit quad*4+r, batch b) LOCAL ----
        const f32x4 accF = aFe + aFo;
        const f32x4 accI = aIe + aIo;
        const f32x4 accA = aAe + aAo;
        const f32x4 accO = aOe + aOo;
        float hs[4];
#pragma unroll
        for (int r = 0; r < 4; ++r) {
            const float fv = sigmoid_fast(accF[r] + (float)gxa[r]);
            const float iv = sigmoid_fast(accI[r] + (float)gxa[4 + r]);
            const float av = tanh_fast   (accA[r] + (float)gxb[r]);
            const float ov = sigmoid_fast(accO[r] + (float)gxb[4 + r]);
            cs[r] = fv * cs[r] + iv * av;
            hs[r] = ov * tanh_fast(cs[r]);
        }

        const int hidx = b * HD_ + blk * UPB + quad * 4;
        // out stores FIRST: acks drain inside the publish vmcnt(0),
        // overlapped with the h MALL ack (r12 lesson).
        *reinterpret_cast<float4*>(
            out + ((size_t)b * T_ + t) * HD_ + blk * UPB + quad * 4) =
            make_float4(hs[0], hs[1], hs[2], hs[3]);
        if (t == T_ - 1) {
            *reinterpret_cast<float4*>(out + (size_t)M1_ * HD_ + hidx) =
                make_float4(hs[0], hs[1], hs[2], hs[3]);
            *reinterpret_cast<float4*>(
                out + (size_t)M1_ * HD_ + B_ * HD_ + hidx) =
                make_float4(cs[0], cs[1], cs[2], cs[3]);
        }
        if (t < T_ - 1) {
            const unsigned long long hp =
                (unsigned long long)bf16_bits(hs[0]) |
                ((unsigned long long)bf16_bits(hs[1]) << 16) |
                ((unsigned long long)bf16_bits(hs[2]) << 32) |
                ((unsigned long long)bf16_bits(hs[3]) << 48);
            *reinterpret_cast<volatile unsigned long long*>(hout + hidx) = hp;
            // drain own h (MALL) + out acks, block barrier, ONE flag store.
            __asm__ __volatile__("s_waitcnt vmcnt(0)" ::: "memory");
            asm volatile("s_barrier" ::: "memory");
            if (tid == 0)
                *reinterpret_cast<volatile int*>(flags + blk) = t + 1;
            __asm__ __volatile__("" ::: "memory");
            // prefetch next step's gx: a full step of latency to hide.
            const size_t gb = (((size_t)(t + 1) * NBLK + blk) * 256 + tid) * 16;
            gxa_n = *reinterpret_cast<const bf16x8*>(gates3 + gb);
            gxb_n = *reinterpret_cast<const bf16x8*>(gates3 + gb + 8);
        }
    }
}

// -------------------------------------------------------------- launcher ----
extern "C" void kernel_launch(void* const* d_in, const int* in_sizes, int n_in,
                              void* d_out, int out_size, void* d_ws, size_t ws_size,
                              hipStream_t stream) {
    const float* x  = (const float*)d_in[0];
    const float* Wi = (const float*)d_in[1];
    const float* bi = (const float*)d_in[2];
    const float* Wh = (const float*)d_in[3];
    const float* bh = (const float*)d_in[4];
    float* out = (float*)d_out;

    char* ws = (char*)d_ws;
    size_t off = 0;
    bf16* xb     = (bf16*)(ws + off); off += (size_t)M1_ * ID_ * 2;       // 16 MB
    bf16* wiT    = (bf16*)(ws + off); off += (size_t)NG_ * ID_ * 2;       // 4 MB
    bf16* whT    = (bf16*)(ws + off); off += (size_t)NG_ * HD_ * 2;       // 8 MB
    bf16* gates3 = (bf16*)(ws + off); off += (size_t)T_ * B_ * NG_ * 2;   // 128 MB
    bf16* hbuf   = (bf16*)(ws + off); off += (size_t)2 * B_ * HD_ * 2;    // 256 KB
    int* flags   = (int*)(ws + off);  off += (size_t)NBLK * 4 * 16 * 4;   // 16 KB

    prep_kernel<<<8192, 256, 0, stream>>>(x, Wi, Wh, xb, wiT, whT, hbuf, flags);
    gates_gemm_kernel<<<dim3(128, 32), 256, 0, stream>>>(xb, wiT, bi, bh, gates3);

    lstm_persistent_kernel<<<dim3(NBLK), dim3(320), 0, stream>>>(
        gates3, whT, hbuf, out, flags);
}

// Round 11
// 2372.320 us; speedup vs baseline: 1.0330x; 1.0330x over previous
//
#include <hip/hip_runtime.h>
#include <hip/hip_bf16.h>

// LSTM B=64, T=256, ID=512, HD=1024. Gates F,I,A,O.
// Round 15: REVERT r14 (arrival-gating regressed +21%: no-sleep poller
// sharing a SIMD + serial LDS-relay spins). New lever from the r12/r13
// budget fit (step = S~2.35 + L_lds + M_mall): r13's 4 waves all read the
// SAME 128 Wh A-frags from LDS -> 512 KB/CU/step on the LDS port (~2.5us,
// the largest term after sync). Fix: 2 waves x (64 m-rows x 32 batches):
// per kk each A-frag is ds_read ONCE and reused for BOTH n-tiles from
// registers -> per-CU A-reads 512->256 KB. MALL h volume per block stays
// 128 KB (each wave loads only its own 32 batches). Gate-locality kept
// (wave holds all 4 gate m-tiles). Counted vmcnt(16) issue-pairs.
// Poll sleep dropped (load-latency already paces the loop).

#define B_  64
#define T_  256
#define ID_ 512
#define HD_ 1024
#define NG_ 4096
#define M1_ (B_ * T_)
#define NBLK 64
#define UPB  16

typedef __bf16 bf16x8 __attribute__((ext_vector_type(8)));
typedef float  f32x4  __attribute__((ext_vector_type(4)));
typedef int    i32x4  __attribute__((ext_vector_type(4)));
typedef short  s16x4  __attribute__((ext_vector_type(4)));

using bf16 = __hip_bfloat16;

__device__ __forceinline__ float sigmoid_fast(float x) {
    return 1.0f / (1.0f + __expf(-x));
}
__device__ __forceinline__ float tanh_fast(float x) {
    return 1.0f - 2.0f / (__expf(2.0f * x) + 1.0f);
}
__device__ __forceinline__ unsigned short bf16_bits(float x) {
    union { bf16 h; unsigned short u; } cv;
    cv.h = __float2bfloat16(x);
    return cv.u;
}
__device__ __forceinline__ bf16x8 as_bf16x8(i32x4 v) {
    union { i32x4 i; bf16x8 h; } cv;
    cv.i = v;
    return cv.h;
}

// 8 coherent 16-B loads from one base (offsets 0..448 B), one asm block.
// "=&v" EARLY-CLOBBER is load-bearing: outputs must not alias the address
// pair (loads 2-8 read %8 after load 1's data can return).
__device__ __forceinline__ void issue8(i32x4* dst, const bf16* gbase) {
    asm volatile(
        "global_load_dwordx4 %0, %8, off sc0 sc1\n\t"
        "global_load_dwordx4 %1, %8, off offset:64 sc0 sc1\n\t"
        "global_load_dwordx4 %2, %8, off offset:128 sc0 sc1\n\t"
        "global_load_dwordx4 %3, %8, off offset:192 sc0 sc1\n\t"
        "global_load_dwordx4 %4, %8, off offset:256 sc0 sc1\n\t"
        "global_load_dwordx4 %5, %8, off offset:320 sc0 sc1\n\t"
        "global_load_dwordx4 %6, %8, off offset:384 sc0 sc1\n\t"
        "global_load_dwordx4 %7, %8, off offset:448 sc0 sc1"
        : "=&v"(dst[0]), "=&v"(dst[1]), "=&v"(dst[2]), "=&v"(dst[3]),
          "=&v"(dst[4]), "=&v"(dst[5]), "=&v"(dst[6]), "=&v"(dst[7])
        : "v"(gbase));
}

// ---------------------------------------------------------------- prep ----
__global__ __launch_bounds__(256) void prep_kernel(
    const float* __restrict__ x, const float* __restrict__ Wi,
    const float* __restrict__ Wh, bf16* __restrict__ xb,
    bf16* __restrict__ wiT, bf16* __restrict__ whT,
    bf16* __restrict__ hbuf, int* __restrict__ flags) {
    const int tid = blockIdx.x * 256 + threadIdx.x;  // [0, 2097152)

    if (tid < NBLK * 4 * 16) flags[tid] = 0;          // covers 64 block flags
    if (tid < (B_ * HD_) / 4)                         // h[-1] = 0 (buf0)
        *reinterpret_cast<s16x4*>(hbuf + (size_t)tid * 4) = s16x4{0, 0, 0, 0};

    const float4 v = reinterpret_cast<const float4*>(x)[tid];
    bf16 tmp[4] = { __float2bfloat16(v.x), __float2bfloat16(v.y),
                    __float2bfloat16(v.z), __float2bfloat16(v.w) };
    *reinterpret_cast<s16x4*>(xb + 4 * (size_t)tid) =
        *reinterpret_cast<s16x4*>(tmp);

    {   // WiT[n][k] = Wi[k][n]
        const int n = tid >> 9, k = tid & 511;
        wiT[tid] = __float2bfloat16(Wi[(size_t)k * NG_ + n]);
    }
    for (int e = 0; e < 2; ++e) {  // WhT[n][k] = Wh[k][n]
        const int idx = 2 * tid + e;
        const int n = idx >> 10, k = idx & 1023;
        whT[idx] = __float2bfloat16(Wh[(size_t)k * NG_ + n]);
    }
}

// ---------------------------------------------------- phase-1 gates GEMM ----
// gates3 layout: [t][blk(64)][tid(128)][32] bf16, element e = nt*16+g*4+r
// for thread tid = w*64 + quad*16 + l15 owning
// (unit blk*16+quad*4+r, batch w*32+nt*16+l15).
__global__ __launch_bounds__(256) void gates_gemm_kernel(
    const bf16* __restrict__ xb, const bf16* __restrict__ wiT,
    const float* __restrict__ bi, const float* __restrict__ bh,
    bf16* __restrict__ gates3) {
    __shared__ __align__(16) bf16 As[128 * 40];
    __shared__ __align__(16) bf16 Bs[128 * 40];
    const int tid  = threadIdx.x;
    const int lane = tid & 63, wave = tid >> 6;
    const int wm = wave >> 1, wn = wave & 1;
    const int l15 = lane & 15, quad = lane >> 4;
    const int row0 = blockIdx.x * 128, col0 = blockIdx.y * 128;

    f32x4 acc[4][4];
    for (int i = 0; i < 4; ++i)
        for (int j = 0; j < 4; ++j) acc[i][j] = f32x4{0.f, 0.f, 0.f, 0.f};

    for (int kt = 0; kt < ID_ / 32; ++kt) {
        const int k0 = kt * 32;
        for (int L = tid; L < 512; L += 256) {
            const int r = L >> 2, s = L & 3;
            *reinterpret_cast<i32x4*>(&As[r * 40 + s * 8]) =
                *reinterpret_cast<const i32x4*>(xb + (size_t)(row0 + r) * ID_ + k0 + s * 8);
            *reinterpret_cast<i32x4*>(&Bs[r * 40 + s * 8]) =
                *reinterpret_cast<const i32x4*>(wiT + (size_t)(col0 + r) * ID_ + k0 + s * 8);
        }
        __syncthreads();
        bf16x8 af[4], bfv[4];
        for (int mt = 0; mt < 4; ++mt)
            af[mt] = *reinterpret_cast<const bf16x8*>(
                &As[(wm * 64 + mt * 16 + l15) * 40 + quad * 8]);
        for (int nt = 0; nt < 4; ++nt)
            bfv[nt] = *reinterpret_cast<const bf16x8*>(
                &Bs[(wn * 64 + nt * 16 + l15) * 40 + quad * 8]);
        for (int mt = 0; mt < 4; ++mt)
            for (int nt = 0; nt < 4; ++nt)
                acc[mt][nt] = __builtin_amdgcn_mfma_f32_16x16x32_bf16(
                    af[mt], bfv[nt], acc[mt][nt], 0, 0, 0);
        __syncthreads();
    }
    // epilogue: +(bi+bh), store to gates3 in persistent-kernel acc order
    for (int mt = 0; mt < 4; ++mt) {
        for (int nt = 0; nt < 4; ++nt) {
            const int cg = col0 + wn * 64 + nt * 16 + l15;
            const int g = cg >> 10, u = cg & 1023;      // gate, hidden unit
            const int blk = u >> 4, ul = u & 15;
            const int q2 = ul >> 2, r2 = ul & 3;
            const float bias = bi[cg] + bh[cg];
            for (int r = 0; r < 4; ++r) {
                const int rg = row0 + wm * 64 + mt * 16 + quad * 4 + r;
                const int b = rg >> 8, t = rg & 255;    // row = b*T + t
                const int w2 = b >> 5, nt2 = (b >> 4) & 1;
                const int tid2 = w2 * 64 + q2 * 16 + (b & 15);
                const int e = nt2 * 16 + g * 4 + r2;
                gates3[(((size_t)t * NBLK + blk) * 128 + tid2) * 32 + e] =
                    __float2bfloat16(acc[mt][nt][r] + bias);
            }
        }
    }
}

// ------------------------------------------------- persistent LSTM steps ----
// 128 threads = 2 waves; wave w owns batches [w*32, w*32+32) as two n-tiles.
// LDS Wh tile: 64 m-rows (4 gates x 16 units) x 1024 k, 128 KB.
// Element layout: kk*2048 + sel*512 + lane*8 (sel = gate) -- conflict-free.
__global__ __launch_bounds__(128, 1) void lstm_persistent_kernel(
    const bf16* __restrict__ gates3, const bf16* __restrict__ whT,
    bf16* __restrict__ hbuf, float* __restrict__ out, int* __restrict__ flags) {
    __shared__ __align__(16) bf16 whs[32 * 4 * 64 * 8];   // 128 KB
    const int tid  = threadIdx.x;               // 0..127
    const int lane = tid & 63, w = tid >> 6;
    const int l15 = lane & 15, quad = lane >> 4;
    const int blk = blockIdx.x;                 // units [blk*16, blk*16+16)

    // ---- stage Wh A-tile into LDS (once), linear 16B writes ----
    for (int c = tid; c < 8192; c += 128) {
        const int kk = c >> 8, sel = (c >> 6) & 3, ln = c & 63;
        const size_t wrow = (size_t)(sel * HD_ + blk * UPB + (ln & 15));
        const int col = (ln >> 4) * 8 + kk * 32;
        *reinterpret_cast<i32x4*>(whs + (size_t)c * 8) =
            *reinterpret_cast<const i32x4*>(whT + wrow * HD_ + col);
    }
    __syncthreads();

    const bf16* wb = whs + (size_t)lane * 8;    // + kk*2048 + sel*512

    const int b0 = w * 32 + l15;                // nt0 batch
    const int b1 = b0 + 16;                     // nt1 batch
    float cs0[4] = {0.f, 0.f, 0.f, 0.f};
    float cs1[4] = {0.f, 0.f, 0.f, 0.f};

    // block flags[0..63]: wave 0 lane i spins on flags[i] (busy poll --
    // load latency alone paces it); wave 1 released by s_barrier.
    const volatile int* pf = (const volatile int*)(flags + lane);

    // gx: 32 bf16 (4 gates x 4 r x 2 nt) contiguous per thread, dbuffered.
    const bf16* gx0 = gates3 + ((size_t)blk * 128 + tid) * 32;
    bf16x8 g0n = *reinterpret_cast<const bf16x8*>(gx0);        // nt0 F,I
    bf16x8 g1n = *reinterpret_cast<const bf16x8*>(gx0 + 8);    // nt0 A,O
    bf16x8 g2n = *reinterpret_cast<const bf16x8*>(gx0 + 16);   // nt1 F,I
    bf16x8 g3n = *reinterpret_cast<const bf16x8*>(gx0 + 24);   // nt1 A,O

    for (int t = 0; t < T_; ++t) {
        const bf16* hin  = hbuf + (size_t)(t & 1) * (B_ * HD_);
        bf16*       hout = hbuf + (size_t)((t + 1) & 1) * (B_ * HD_);
        const bf16x8 g0 = g0n, g1 = g1n, g2 = g2n, g3 = g3n;

        if (t > 0) {
            if (w == 0) {
                while (*pf < t) {}
            }
            asm volatile("s_barrier" ::: "memory");
        }

        f32x4 aF0{0.f,0.f,0.f,0.f}, aI0{0.f,0.f,0.f,0.f};
        f32x4 aA0{0.f,0.f,0.f,0.f}, aO0{0.f,0.f,0.f,0.f};
        f32x4 aF1{0.f,0.f,0.f,0.f}, aI1{0.f,0.f,0.f,0.f};
        f32x4 aA1{0.f,0.f,0.f,0.f}, aO1{0.f,0.f,0.f,0.f};

        const bf16* base0 = hin + (size_t)b0 * HD_ + quad * 8;
        const bf16* base1 = hin + (size_t)b1 * HD_ + quad * 8;
        i32x4 hbA0[8], hbA1[8], hbB0[8], hbB1[8];

        // one ds_read per A-frag, reused for BOTH n-tiles from registers:
        // 4 ds_reads + 8 MFMAs per kk (r13 did 8 ds_reads for the same).
        auto consumePair = [&](const i32x4* h0, const i32x4* h1, const int kkb) {
#pragma unroll
            for (int i = 0; i < 8; ++i) {
                const int kk = kkb + i;
                const bf16* f = wb + (size_t)kk * 2048;
                const bf16x8 wF = *reinterpret_cast<const bf16x8*>(f);
                const bf16x8 wI = *reinterpret_cast<const bf16x8*>(f + 512);
                const bf16x8 wA = *reinterpret_cast<const bf16x8*>(f + 1024);
                const bf16x8 wO = *reinterpret_cast<const bf16x8*>(f + 1536);
                const bf16x8 h0v = as_bf16x8(h0[i]);
                const bf16x8 h1v = as_bf16x8(h1[i]);
                aF0 = __builtin_amdgcn_mfma_f32_16x16x32_bf16(wF, h0v, aF0, 0, 0, 0);
                aF1 = __builtin_amdgcn_mfma_f32_16x16x32_bf16(wF, h1v, aF1, 0, 0, 0);
                aI0 = __builtin_amdgcn_mfma_f32_16x16x32_bf16(wI, h0v, aI0, 0, 0, 0);
                aI1 = __builtin_amdgcn_mfma_f32_16x16x32_bf16(wI, h1v, aI1, 0, 0, 0);
                aA0 = __builtin_amdgcn_mfma_f32_16x16x32_bf16(wA, h0v, aA0, 0, 0, 0);
                aA1 = __builtin_amdgcn_mfma_f32_16x16x32_bf16(wA, h1v, aA1, 0, 0, 0);
                aO0 = __builtin_amdgcn_mfma_f32_16x16x32_bf16(wO, h0v, aO0, 0, 0, 0);
                aO1 = __builtin_amdgcn_mfma_f32_16x16x32_bf16(wO, h1v, aO1, 0, 0, 0);
            }
        };

        // issue-pairs of 16 loads (both n-tiles of one kk-octet), counted
        // vmcnt(16): the next pair is always in flight during consumption.
        issue8(hbA0, base0);        issue8(hbA1, base1);          // kk 0..7
        issue8(hbB0, base0 + 256);  issue8(hbB1, base1 + 256);    // kk 8..15
        asm volatile("s_waitcnt vmcnt(16)" ::: "memory");
        __builtin_amdgcn_sched_barrier(0);
        consumePair(hbA0, hbA1, 0);
        issue8(hbA0, base0 + 512);  issue8(hbA1, base1 + 512);    // kk 16..23
        asm volatile("s_waitcnt vmcnt(16)" ::: "memory");
        __builtin_amdgcn_sched_barrier(0);
        consumePair(hbB0, hbB1, 8);
        issue8(hbB0, base0 + 768);  issue8(hbB1, base1 + 768);    // kk 24..31
        asm volatile("s_waitcnt vmcnt(16)" ::: "memory");
        __builtin_amdgcn_sched_barrier(0);
        consumePair(hbA0, hbA1, 16);
        asm volatile("s_waitcnt vmcnt(0)" ::: "memory");
        __builtin_amdgcn_sched_barrier(0);
        consumePair(hbB0, hbB1, 24);

        // ---- activations: all 4 gates local per (unit, batch) ----
        float hs0[4], hs1[4];
#pragma unroll
        for (int r = 0; r < 4; ++r) {
            const float F0 = sigmoid_fast(aF0[r] + (float)g0[r]);
            const float I0 = sigmoid_fast(aI0[r] + (float)g0[4 + r]);
            const float A0 = tanh_fast   (aA0[r] + (float)g1[r]);
            const float O0 = sigmoid_fast(aO0[r] + (float)g1[4 + r]);
            cs0[r] = F0 * cs0[r] + I0 * A0;
            hs0[r] = O0 * tanh_fast(cs0[r]);
            const float F1 = sigmoid_fast(aF1[r] + (float)g2[r]);
            const float I1 = sigmoid_fast(aI1[r] + (float)g2[4 + r]);
            const float A1 = tanh_fast   (aA1[r] + (float)g3[r]);
            const float O1 = sigmoid_fast(aO1[r] + (float)g3[4 + r]);
            cs1[r] = F1 * cs1[r] + I1 * A1;
            hs1[r] = O1 * tanh_fast(cs1[r]);
        }

        const int hidx0 = b0 * HD_ + blk * UPB + quad * 4;
        const int hidx1 = b1 * HD_ + blk * UPB + quad * 4;
        // out stores FIRST: acks drain inside the publish vmcnt(0),
        // overlapped with the h MALL acks (r12 lesson).
        *reinterpret_cast<float4*>(
            out + ((size_t)b0 * T_ + t) * HD_ + blk * UPB + quad * 4) =
            make_float4(hs0[0], hs0[1], hs0[2], hs0[3]);
        *reinterpret_cast<float4*>(
            out + ((size_t)b1 * T_ + t) * HD_ + blk * UPB + quad * 4) =
            make_float4(hs1[0], hs1[1], hs1[2], hs1[3]);
        if (t == T_ - 1) {
            *reinterpret_cast<float4*>(out + (size_t)M1_ * HD_ + hidx0) =
                make_float4(hs0[0], hs0[1], hs0[2], hs0[3]);
            *reinterpret_cast<float4*>(out + (size_t)M1_ * HD_ + hidx1) =
                make_float4(hs1[0], hs1[1], hs1[2], hs1[3]);
            *reinterpret_cast<float4*>(
                out + (size_t)M1_ * HD_ + B_ * HD_ + hidx0) =
                make_float4(cs0[0], cs0[1], cs0[2], cs0[3]);
            *reinterpret_cast<float4*>(
                out + (size_t)M1_ * HD_ + B_ * HD_ + hidx1) =
                make_float4(cs1[0], cs1[1], cs1[2], cs1[3]);
        }
        if (t < T_ - 1) {
            const unsigned long long hp0 =
                (unsigned long long)bf16_bits(hs0[0]) |
                ((unsigned long long)bf16_bits(hs0[1]) << 16) |
                ((unsigned long long)bf16_bits(hs0[2]) << 32) |
                ((unsigned long long)bf16_bits(hs0[3]) << 48);
            const unsigned long long hp1 =
                (unsigned long long)bf16_bits(hs1[0]) |
                ((unsigned long long)bf16_bits(hs1[1]) << 16) |
                ((unsigned long long)bf16_bits(hs1[2]) << 32) |
                ((unsigned long long)bf16_bits(hs1[3]) << 48);
            *reinterpret_cast<volatile unsigned long long*>(hout + hidx0) = hp0;
            *reinterpret_cast<volatile unsigned long long*>(hout + hidx1) = hp1;
            // drain own h (MALL) + out acks, block barrier, ONE flag store.
            __asm__ __volatile__("s_waitcnt vmcnt(0)" ::: "memory");
            asm volatile("s_barrier" ::: "memory");
            if (tid == 0)
                *reinterpret_cast<volatile int*>(flags + blk) = t + 1;
            __asm__ __volatile__("" ::: "memory");
            // prefetch next step's gx: a full step of latency to hide.
            const bf16* gxp = gates3 +
                (((size_t)(t + 1) * NBLK + blk) * 128 + tid) * 32;
            g0n = *reinterpret_cast<const bf16x8*>(gxp);
            g1n = *reinterpret_cast<const bf16x8*>(gxp + 8);
            g2n = *reinterpret_cast<const bf16x8*>(gxp + 16);
            g3n = *reinterpret_cast<const bf16x8*>(gxp + 24);
        }
    }
}

// -------------------------------------------------------------- launcher ----
extern "C" void kernel_launch(void* const* d_in, const int* in_sizes, int n_in,
                              void* d_out, int out_size, void* d_ws, size_t ws_size,
                              hipStream_t stream) {
    const float* x  = (const float*)d_in[0];
    const float* Wi = (const float*)d_in[1];
    const float* bi = (const float*)d_in[2];
    const float* Wh = (const float*)d_in[3];
    const float* bh = (const float*)d_in[4];
    float* out = (float*)d_out;

    char* ws = (char*)d_ws;
    size_t off = 0;
    bf16* xb     = (bf16*)(ws + off); off += (size_t)M1_ * ID_ * 2;       // 16 MB
    bf16* wiT    = (bf16*)(ws + off); off += (size_t)NG_ * ID_ * 2;       // 4 MB
    bf16* whT    = (bf16*)(ws + off); off += (size_t)NG_ * HD_ * 2;       // 8 MB
    bf16* gates3 = (bf16*)(ws + off); off += (size_t)T_ * B_ * NG_ * 2;   // 128 MB
    bf16* hbuf   = (bf16*)(ws + off); off += (size_t)2 * B_ * HD_ * 2;    // 256 KB
    int* flags   = (int*)(ws + off);  off += (size_t)NBLK * 4 * 16 * 4;   // 16 KB

    prep_kernel<<<8192, 256, 0, stream>>>(x, Wi, Wh, xb, wiT, whT, hbuf, flags);
    gates_gemm_kernel<<<dim3(128, 32), 256, 0, stream>>>(xb, wiT, bi, bh, gates3);

    lstm_persistent_kernel<<<dim3(NBLK), dim3(128), 0, stream>>>(
        gates3, whT, hbuf, out, flags);
}

// Round 12
// 1891.563 us; speedup vs baseline: 1.2955x; 1.2542x over previous
//
#include <hip/hip_runtime.h>
#include <hip/hip_bf16.h>

// LSTM B=64, T=256, ID=512, HD=1024. Gates F,I,A,O.
// Round 16: REVERT persistent to r13 (best verified: 1667us; r14/r15
// structural bets both regressed +20%). New lever: the ~380us prep+GEMM
// tail. r13's GEMM epilogue did 64 scalar 2B stores/thread into a layout
// that scatters each wave across 64 cache lines (~67M scattered stores for
// the 128MB gates3). Fix: gates3 in GEMM-NATURAL layout [b*T+t][4H] ->
// epilogue stores are lane-contiguous (16 lanes = one 32B segment, ~8x
// fewer transactions). Persistent absorbs it as 4x8B gx loads (one per
// gate), still prefetched a full step ahead -> off the critical path.
// Persistent kernel otherwise IDENTICAL to r13 (UPB=16 gate-local
// activations, 128KB LDS Wh conflict-free, issue8 "=&v", counted vmcnt(8),
// wave0-poll + s_sleep(2), publish drain -> barrier -> single block flag).

#define B_  64
#define T_  256
#define ID_ 512
#define HD_ 1024
#define NG_ 4096
#define M1_ (B_ * T_)
#define NBLK 64
#define UPB  16

typedef __bf16 bf16x8 __attribute__((ext_vector_type(8)));
typedef __bf16 bf16x4v __attribute__((ext_vector_type(4)));
typedef float  f32x4  __attribute__((ext_vector_type(4)));
typedef int    i32x4  __attribute__((ext_vector_type(4)));
typedef short  s16x4  __attribute__((ext_vector_type(4)));

using bf16 = __hip_bfloat16;

__device__ __forceinline__ float sigmoid_fast(float x) {
    return 1.0f / (1.0f + __expf(-x));
}
__device__ __forceinline__ float tanh_fast(float x) {
    return 1.0f - 2.0f / (__expf(2.0f * x) + 1.0f);
}
__device__ __forceinline__ unsigned short bf16_bits(float x) {
    union { bf16 h; unsigned short u; } cv;
    cv.h = __float2bfloat16(x);
    return cv.u;
}
__device__ __forceinline__ bf16x8 as_bf16x8(i32x4 v) {
    union { i32x4 i; bf16x8 h; } cv;
    cv.i = v;
    return cv.h;
}

// 8 coherent 16-B loads from one base (offsets 0..448 B), one asm block.
// "=&v" EARLY-CLOBBER is load-bearing: outputs must not alias the address
// pair (loads 2-8 read %8 after load 1's data can return).
__device__ __forceinline__ void issue8(i32x4* dst, const bf16* gbase) {
    asm volatile(
        "global_load_dwordx4 %0, %8, off sc0 sc1\n\t"
        "global_load_dwordx4 %1, %8, off offset:64 sc0 sc1\n\t"
        "global_load_dwordx4 %2, %8, off offset:128 sc0 sc1\n\t"
        "global_load_dwordx4 %3, %8, off offset:192 sc0 sc1\n\t"
        "global_load_dwordx4 %4, %8, off offset:256 sc0 sc1\n\t"
        "global_load_dwordx4 %5, %8, off offset:320 sc0 sc1\n\t"
        "global_load_dwordx4 %6, %8, off offset:384 sc0 sc1\n\t"
        "global_load_dwordx4 %7, %8, off offset:448 sc0 sc1"
        : "=&v"(dst[0]), "=&v"(dst[1]), "=&v"(dst[2]), "=&v"(dst[3]),
          "=&v"(dst[4]), "=&v"(dst[5]), "=&v"(dst[6]), "=&v"(dst[7])
        : "v"(gbase));
}

// ---------------------------------------------------------------- prep ----
__global__ __launch_bounds__(256) void prep_kernel(
    const float* __restrict__ x, const float* __restrict__ Wi,
    const float* __restrict__ Wh, bf16* __restrict__ xb,
    bf16* __restrict__ wiT, bf16* __restrict__ whT,
    bf16* __restrict__ hbuf, int* __restrict__ flags) {
    const int tid = blockIdx.x * 256 + threadIdx.x;  // [0, 2097152)

    if (tid < NBLK * 4 * 16) flags[tid] = 0;          // covers 64 block flags
    if (tid < (B_ * HD_) / 4)                         // h[-1] = 0 (buf0)
        *reinterpret_cast<s16x4*>(hbuf + (size_t)tid * 4) = s16x4{0, 0, 0, 0};

    const float4 v = reinterpret_cast<const float4*>(x)[tid];
    bf16 tmp[4] = { __float2bfloat16(v.x), __float2bfloat16(v.y),
                    __float2bfloat16(v.z), __float2bfloat16(v.w) };
    *reinterpret_cast<s16x4*>(xb + 4 * (size_t)tid) =
        *reinterpret_cast<s16x4*>(tmp);

    {   // WiT[n][k] = Wi[k][n]
        const int n = tid >> 9, k = tid & 511;
        wiT[tid] = __float2bfloat16(Wi[(size_t)k * NG_ + n]);
    }
    for (int e = 0; e < 2; ++e) {  // WhT[n][k] = Wh[k][n]
        const int idx = 2 * tid + e;
        const int n = idx >> 10, k = idx & 1023;
        whT[idx] = __float2bfloat16(Wh[(size_t)k * NG_ + n]);
    }
}

// ---------------------------------------------------- phase-1 gates GEMM ----
// gates3 layout: NATURAL [row = b*T + t][col = gate*1024 + unit] bf16.
// Epilogue stores are lane-contiguous (l15 -> consecutive cols).
__global__ __launch_bounds__(256) void gates_gemm_kernel(
    const bf16* __restrict__ xb, const bf16* __restrict__ wiT,
    const float* __restrict__ bi, const float* __restrict__ bh,
    bf16* __restrict__ gates3) {
    __shared__ __align__(16) bf16 As[128 * 40];
    __shared__ __align__(16) bf16 Bs[128 * 40];
    const int tid  = threadIdx.x;
    const int lane = tid & 63, wave = tid >> 6;
    const int wm = wave >> 1, wn = wave & 1;
    const int l15 = lane & 15, quad = lane >> 4;
    const int row0 = blockIdx.x * 128, col0 = blockIdx.y * 128;

    f32x4 acc[4][4];
    for (int i = 0; i < 4; ++i)
        for (int j = 0; j < 4; ++j) acc[i][j] = f32x4{0.f, 0.f, 0.f, 0.f};

    for (int kt = 0; kt < ID_ / 32; ++kt) {
        const int k0 = kt * 32;
        for (int L = tid; L < 512; L += 256) {
            const int r = L >> 2, s = L & 3;
            *reinterpret_cast<i32x4*>(&As[r * 40 + s * 8]) =
                *reinterpret_cast<const i32x4*>(xb + (size_t)(row0 + r) * ID_ + k0 + s * 8);
            *reinterpret_cast<i32x4*>(&Bs[r * 40 + s * 8]) =
                *reinterpret_cast<const i32x4*>(wiT + (size_t)(col0 + r) * ID_ + k0 + s * 8);
        }
        __syncthreads();
        bf16x8 af[4], bfv[4];
        for (int mt = 0; mt < 4; ++mt)
            af[mt] = *reinterpret_cast<const bf16x8*>(
                &As[(wm * 64 + mt * 16 + l15) * 40 + quad * 8]);
        for (int nt = 0; nt < 4; ++nt)
            bfv[nt] = *reinterpret_cast<const bf16x8*>(
                &Bs[(wn * 64 + nt * 16 + l15) * 40 + quad * 8]);
        for (int mt = 0; mt < 4; ++mt)
            for (int nt = 0; nt < 4; ++nt)
                acc[mt][nt] = __builtin_amdgcn_mfma_f32_16x16x32_bf16(
                    af[mt], bfv[nt], acc[mt][nt], 0, 0, 0);
        __syncthreads();
    }
    // epilogue: +(bi+bh), natural-layout coalesced stores
    for (int mt = 0; mt < 4; ++mt) {
        for (int nt = 0; nt < 4; ++nt) {
            const int cg = col0 + wn * 64 + nt * 16 + l15;
            const float bias = bi[cg] + bh[cg];
            for (int r = 0; r < 4; ++r) {
                const int rg = row0 + wm * 64 + mt * 16 + quad * 4 + r;
                gates3[(size_t)rg * NG_ + cg] =
                    __float2bfloat16(acc[mt][nt][r] + bias);
            }
        }
    }
}

// ------------------------------------------------- persistent LSTM steps ----
// r13 structure verbatim. 256 threads = 4 waves; wave w owns batches
// [w*16, w*16+16); thread owns (batch b = w*16+l15, units quad*4..+3).
// LDS Wh tile: 64 m-rows (4 gates x 16 units) x 1024 k, 128 KB.
// Element layout: kk*2048 + sel*512 + lane*8 (sel = gate) -- conflict-free.
__global__ __launch_bounds__(256, 1) void lstm_persistent_kernel(
    const bf16* __restrict__ gates3, const bf16* __restrict__ whT,
    bf16* __restrict__ hbuf, float* __restrict__ out, int* __restrict__ flags) {
    __shared__ __align__(16) bf16 whs[32 * 4 * 64 * 8];   // 128 KB
    const int tid  = threadIdx.x;
    const int lane = tid & 63, w = tid >> 6;
    const int l15 = lane & 15, quad = lane >> 4;
    const int blk = blockIdx.x;                 // units [blk*16, blk*16+16)

    // ---- stage Wh A-tile into LDS (once), linear 16B writes ----
    for (int c = tid; c < 8192; c += 256) {
        const int kk = c >> 8, sel = (c >> 6) & 3, ln = c & 63;
        const size_t wrow = (size_t)(sel * HD_ + blk * UPB + (ln & 15));
        const int col = (ln >> 4) * 8 + kk * 32;
        *reinterpret_cast<i32x4*>(whs + (size_t)c * 8) =
            *reinterpret_cast<const i32x4*>(whT + wrow * HD_ + col);
    }
    __syncthreads();

    const bf16* wb = whs + (size_t)lane * 8;    // + kk*2048 + sel*512

    const int b = w * 16 + l15;                 // batch row
    float cs[4] = {0.f, 0.f, 0.f, 0.f};

    // block flags[0..63]: wave 0 lane i polls flags[i]; waves 1-3 released
    // by s_barrier. Producer: drain -> s_barrier -> tid0 stores flags[blk].
    const volatile int* pf = (const volatile int*)(flags + lane);

    // gx: natural layout -> 4 x 8B loads (one per gate), dbuffered one
    // step ahead (issued after the publish, never on the critical path).
    const bf16* gxb0 = gates3 + (size_t)b * T_ * NG_ + blk * UPB + quad * 4;
    bf16x4v gF_n = *reinterpret_cast<const bf16x4v*>(gxb0);
    bf16x4v gI_n = *reinterpret_cast<const bf16x4v*>(gxb0 + 1024);
    bf16x4v gA_n = *reinterpret_cast<const bf16x4v*>(gxb0 + 2048);
    bf16x4v gO_n = *reinterpret_cast<const bf16x4v*>(gxb0 + 3072);

    for (int t = 0; t < T_; ++t) {
        const bf16* hin  = hbuf + (size_t)(t & 1) * (B_ * HD_);
        bf16*       hout = hbuf + (size_t)((t + 1) & 1) * (B_ * HD_);
        const bf16x4v gF = gF_n, gI = gI_n, gA = gA_n, gO = gO_n;

        if (t > 0) {
            if (w == 0) {
                while (*pf < t) __builtin_amdgcn_s_sleep(2);
            }
            asm volatile("s_barrier" ::: "memory");
        }

        f32x4 aFe{0.f,0.f,0.f,0.f}, aFo{0.f,0.f,0.f,0.f};
        f32x4 aIe{0.f,0.f,0.f,0.f}, aIo{0.f,0.f,0.f,0.f};
        f32x4 aAe{0.f,0.f,0.f,0.f}, aAo{0.f,0.f,0.f,0.f};
        f32x4 aOe{0.f,0.f,0.f,0.f}, aOo{0.f,0.f,0.f,0.f};

        // ---- h B-frags: ping-pong groups of 8, counted vmcnt(8) ----
        const bf16* hb_base = hin + (size_t)b * HD_ + quad * 8;
        i32x4 hbA[8], hbB[8];

        auto consume8 = [&](const i32x4* hbg, const int kkb) {
#pragma unroll
            for (int i = 0; i < 8; i += 2) {
                const int kk = kkb + i;
                const bf16* f0 = wb + (size_t)kk * 2048;
                const bf16* f1 = f0 + 2048;
                const bf16x8 he = as_bf16x8(hbg[i]);
                const bf16x8 ho = as_bf16x8(hbg[i + 1]);
                aFe = __builtin_amdgcn_mfma_f32_16x16x32_bf16(
                    *reinterpret_cast<const bf16x8*>(f0),        he, aFe, 0, 0, 0);
                aIe = __builtin_amdgcn_mfma_f32_16x16x32_bf16(
                    *reinterpret_cast<const bf16x8*>(f0 + 512),  he, aIe, 0, 0, 0);
                aAe = __builtin_amdgcn_mfma_f32_16x16x32_bf16(
                    *reinterpret_cast<const bf16x8*>(f0 + 1024), he, aAe, 0, 0, 0);
                aOe = __builtin_amdgcn_mfma_f32_16x16x32_bf16(
                    *reinterpret_cast<const bf16x8*>(f0 + 1536), he, aOe, 0, 0, 0);
                aFo = __builtin_amdgcn_mfma_f32_16x16x32_bf16(
                    *reinterpret_cast<const bf16x8*>(f1),        ho, aFo, 0, 0, 0);
                aIo = __builtin_amdgcn_mfma_f32_16x16x32_bf16(
                    *reinterpret_cast<const bf16x8*>(f1 + 512),  ho, aIo, 0, 0, 0);
                aAo = __builtin_amdgcn_mfma_f32_16x16x32_bf16(
                    *reinterpret_cast<const bf16x8*>(f1 + 1024), ho, aAo, 0, 0, 0);
                aOo = __builtin_amdgcn_mfma_f32_16x16x32_bf16(
                    *reinterpret_cast<const bf16x8*>(f1 + 1536), ho, aOo, 0, 0, 0);
            }
        };

        issue8(hbA, hb_base);             // kk  0..7
        issue8(hbB, hb_base + 8 * 32);    // kk  8..15
        asm volatile("s_waitcnt vmcnt(8)" ::: "memory");
        __builtin_amdgcn_sched_barrier(0);
        consume8(hbA, 0);
        issue8(hbA, hb_base + 16 * 32);   // kk 16..23
        asm volatile("s_waitcnt vmcnt(8)" ::: "memory");
        __builtin_amdgcn_sched_barrier(0);
        consume8(hbB, 8);
        issue8(hbB, hb_base + 24 * 32);   // kk 24..31
        asm volatile("s_waitcnt vmcnt(8)" ::: "memory");
        __builtin_amdgcn_sched_barrier(0);
        consume8(hbA, 16);
        asm volatile("s_waitcnt vmcnt(0)" ::: "memory");
        __builtin_amdgcn_sched_barrier(0);
        consume8(hbB, 24);

        // ---- activations: all 4 gates local per (unit, batch) ----
        const f32x4 accF = aFe + aFo;
        const f32x4 accI = aIe + aIo;
        const f32x4 accA = aAe + aAo;
        const f32x4 accO = aOe + aOo;
        float hs[4];
#pragma unroll
        for (int r = 0; r < 4; ++r) {
            const float fv = sigmoid_fast(accF[r] + (float)gF[r]);
            const float iv = sigmoid_fast(accI[r] + (float)gI[r]);
            const float av = tanh_fast   (accA[r] + (float)gA[r]);
            const float ov = sigmoid_fast(accO[r] + (float)gO[r]);
            cs[r] = fv * cs[r] + iv * av;
            hs[r] = ov * tanh_fast(cs[r]);
        }

        const int hidx = b * HD_ + blk * UPB + quad * 4;
        // out stores FIRST: acks drain inside the publish vmcnt(0),
        // overlapped with the h MALL ack (r12 lesson).
        *reinterpret_cast<float4*>(
            out + ((size_t)b * T_ + t) * HD_ + blk * UPB + quad * 4) =
            make_float4(hs[0], hs[1], hs[2], hs[3]);
        if (t == T_ - 1) {
            *reinterpret_cast<float4*>(out + (size_t)M1_ * HD_ + hidx) =
                make_float4(hs[0], hs[1], hs[2], hs[3]);
            *reinterpret_cast<float4*>(
                out + (size_t)M1_ * HD_ + B_ * HD_ + hidx) =
                make_float4(cs[0], cs[1], cs[2], cs[3]);
        }
        if (t < T_ - 1) {
            const unsigned long long hp =
                (unsigned long long)bf16_bits(hs[0]) |
                ((unsigned long long)bf16_bits(hs[1]) << 16) |
                ((unsigned long long)bf16_bits(hs[2]) << 32) |
                ((unsigned long long)bf16_bits(hs[3]) << 48);
            *reinterpret_cast<volatile unsigned long long*>(hout + hidx) = hp;
            // drain own h (MALL) + out acks, block barrier, ONE flag store.
            __asm__ __volatile__("s_waitcnt vmcnt(0)" ::: "memory");
            asm volatile("s_barrier" ::: "memory");
            if (tid == 0)
                *reinterpret_cast<volatile int*>(flags + blk) = t + 1;
            __asm__ __volatile__("" ::: "memory");
            // prefetch next step's gx: a full step of latency to hide.
            const bf16* gxp = gates3 +
                ((size_t)b * T_ + (t + 1)) * NG_ + blk * UPB + quad * 4;
            gF_n = *reinterpret_cast<const bf16x4v*>(gxp);
            gI_n = *reinterpret_cast<const bf16x4v*>(gxp + 1024);
            gA_n = *reinterpret_cast<const bf16x4v*>(gxp + 2048);
            gO_n = *reinterpret_cast<const bf16x4v*>(gxp + 3072);
        }
    }
}

// -------------------------------------------------------------- launcher ----
extern "C" void kernel_launch(void* const* d_in, const int* in_sizes, int n_in,
                              void* d_out, int out_size, void* d_ws, size_t ws_size,
                              hipStream_t stream) {
    const float* x  = (const float*)d_in[0];
    const float* Wi = (const float*)d_in[1];
    const float* bi = (const float*)d_in[2];
    const float* Wh = (const float*)d_in[3];
    const float* bh = (const float*)d_in[4];
    float* out = (float*)d_out;

    char* ws = (char*)d_ws;
    size_t off = 0;
    bf16* xb     = (bf16*)(ws + off); off += (size_t)M1_ * ID_ * 2;       // 16 MB
    bf16* wiT    = (bf16*)(ws + off); off += (size_t)NG_ * ID_ * 2;       // 4 MB
    bf16* whT    = (bf16*)(ws + off); off += (size_t)NG_ * HD_ * 2;       // 8 MB
    bf16* gates3 = (bf16*)(ws + off); off += (size_t)T_ * B_ * NG_ * 2;   // 128 MB
    bf16* hbuf   = (bf16*)(ws + off); off += (size_t)2 * B_ * HD_ * 2;    // 256 KB
    int* flags   = (int*)(ws + off);  off += (size_t)NBLK * 4 * 16 * 4;   // 16 KB

    prep_kernel<<<8192, 256, 0, stream>>>(x, Wi, Wh, xb, wiT, whT, hbuf, flags);
    gates_gemm_kernel<<<dim3(128, 32), 256, 0, stream>>>(xb, wiT, bi, bh, gates3);

    lstm_persistent_kernel<<<dim3(NBLK), dim3(256), 0, stream>>>(
        gates3, whT, hbuf, out, flags);
}

// Round 13
// 1864.671 us; speedup vs baseline: 1.3142x; 1.0144x over previous
//
#include <hip/hip_runtime.h>
#include <hip/hip_bf16.h>

// LSTM B=64, T=256, ID=512, HD=1024. Gates F,I,A,O.
// Round 17: LDS-tiled weight transposes. r16 confirmed the tail theory
// (natural gates3 layout: total 2050->1891). Remaining tail ~230us; the
// prep transposes read ONE scalar fp32 at 16KB stride per thread -> 64B
// line per 4B element: ~384MB HBM over-fetch for 24MB useful (~60-90us).
// Fix: classic 64x64 LDS-tile transpose (coalesced float4 reads -> padded
// LDS (stride 65, 2-way = free) -> coalesced 8B bf16 writes).
// GEMM + persistent kernels FROZEN at r16 (best verified: 1891us total,
// 1660us persistent).

#define B_  64
#define T_  256
#define ID_ 512
#define HD_ 1024
#define NG_ 4096
#define M1_ (B_ * T_)
#define NBLK 64
#define UPB  16

typedef __bf16 bf16x8 __attribute__((ext_vector_type(8)));
typedef __bf16 bf16x4v __attribute__((ext_vector_type(4)));
typedef float  f32x4  __attribute__((ext_vector_type(4)));
typedef int    i32x4  __attribute__((ext_vector_type(4)));
typedef short  s16x4  __attribute__((ext_vector_type(4)));

using bf16 = __hip_bfloat16;

__device__ __forceinline__ float sigmoid_fast(float x) {
    return 1.0f / (1.0f + __expf(-x));
}
__device__ __forceinline__ float tanh_fast(float x) {
    return 1.0f - 2.0f / (__expf(2.0f * x) + 1.0f);
}
__device__ __forceinline__ unsigned short bf16_bits(float x) {
    union { bf16 h; unsigned short u; } cv;
    cv.h = __float2bfloat16(x);
    return cv.u;
}
__device__ __forceinline__ bf16x8 as_bf16x8(i32x4 v) {
    union { i32x4 i; bf16x8 h; } cv;
    cv.i = v;
    return cv.h;
}

// 8 coherent 16-B loads from one base (offsets 0..448 B), one asm block.
// "=&v" EARLY-CLOBBER is load-bearing: outputs must not alias the address
// pair (loads 2-8 read %8 after load 1's data can return).
__device__ __forceinline__ void issue8(i32x4* dst, const bf16* gbase) {
    asm volatile(
        "global_load_dwordx4 %0, %8, off sc0 sc1\n\t"
        "global_load_dwordx4 %1, %8, off offset:64 sc0 sc1\n\t"
        "global_load_dwordx4 %2, %8, off offset:128 sc0 sc1\n\t"
        "global_load_dwordx4 %3, %8, off offset:192 sc0 sc1\n\t"
        "global_load_dwordx4 %4, %8, off offset:256 sc0 sc1\n\t"
        "global_load_dwordx4 %5, %8, off offset:320 sc0 sc1\n\t"
        "global_load_dwordx4 %6, %8, off offset:384 sc0 sc1\n\t"
        "global_load_dwordx4 %7, %8, off offset:448 sc0 sc1"
        : "=&v"(dst[0]), "=&v"(dst[1]), "=&v"(dst[2]), "=&v"(dst[3]),
          "=&v"(dst[4]), "=&v"(dst[5]), "=&v"(dst[6]), "=&v"(dst[7])
        : "v"(gbase));
}

// ---------------------------------------------------------------- prep ----
// x conversion (coalesced float4) + flags/hbuf init only.
__global__ __launch_bounds__(256) void prep_kernel(
    const float* __restrict__ x, bf16* __restrict__ xb,
    bf16* __restrict__ hbuf, int* __restrict__ flags) {
    const int tid = blockIdx.x * 256 + threadIdx.x;  // [0, 2097152)

    if (tid < NBLK * 4 * 16) flags[tid] = 0;          // covers 64 block flags
    if (tid < (B_ * HD_) / 4)                         // h[-1] = 0 (buf0)
        *reinterpret_cast<s16x4*>(hbuf + (size_t)tid * 4) = s16x4{0, 0, 0, 0};

    const float4 v = reinterpret_cast<const float4*>(x)[tid];
    bf16 tmp[4] = { __float2bfloat16(v.x), __float2bfloat16(v.y),
                    __float2bfloat16(v.z), __float2bfloat16(v.w) };
    *reinterpret_cast<s16x4*>(xb + 4 * (size_t)tid) =
        *reinterpret_cast<s16x4*>(tmp);
}

// ------------------------------------------------------ weight transpose ----
// 64x64 tiles via padded LDS. blocks 0..511: Wi (K=512); 512..1535: Wh
// (K=1024). Reads: coalesced float4 rows. Writes: 16 threads x 8B = 128B
// contiguous per row of the transposed output. LDS column reads are
// stride-65 -> 2-way bank aliasing (free, m136).
__global__ __launch_bounds__(256) void transpose_kernel(
    const float* __restrict__ Wi, const float* __restrict__ Wh,
    bf16* __restrict__ wiT, bf16* __restrict__ whT) {
    __shared__ float tile[64 * 65];
    int bid = blockIdx.x;
    const float* src;
    bf16* dst;
    int K;
    if (bid < 512) { src = Wi; dst = wiT; K = 512; }
    else           { bid -= 512; src = Wh; dst = whT; K = 1024; }
    const int ktile = bid >> 6, ntile = bid & 63;   // k-tile, n-tile
    const int t  = threadIdx.x;
    const int rr = t >> 4, cc4 = (t & 15) * 4;

#pragma unroll
    for (int i = 0; i < 4; ++i) {
        const int r = rr + 16 * i;                   // source row (k)
        const float4 v = *reinterpret_cast<const float4*>(
            src + (size_t)(ktile * 64 + r) * NG_ + ntile * 64 + cc4);
        tile[r * 65 + cc4 + 0] = v.x;
        tile[r * 65 + cc4 + 1] = v.y;
        tile[r * 65 + cc4 + 2] = v.z;
        tile[r * 65 + cc4 + 3] = v.w;
    }
    __syncthreads();
#pragma unroll
    for (int i = 0; i < 4; ++i) {
        const int r2 = rr + 16 * i;                  // output row (n)
        bf16 o[4];
#pragma unroll
        for (int j = 0; j < 4; ++j)
            o[j] = __float2bfloat16(tile[(cc4 + j) * 65 + r2]);
        *reinterpret_cast<s16x4*>(
            dst + (size_t)(ntile * 64 + r2) * K + ktile * 64 + cc4) =
            *reinterpret_cast<s16x4*>(o);
    }
}

// ---------------------------------------------------- phase-1 gates GEMM ----
// gates3 layout: NATURAL [row = b*T + t][col = gate*1024 + unit] bf16.
// Epilogue stores are lane-contiguous (l15 -> consecutive cols).
__global__ __launch_bounds__(256) void gates_gemm_kernel(
    const bf16* __restrict__ xb, const bf16* __restrict__ wiT,
    const float* __restrict__ bi, const float* __restrict__ bh,
    bf16* __restrict__ gates3) {
    __shared__ __align__(16) bf16 As[128 * 40];
    __shared__ __align__(16) bf16 Bs[128 * 40];
    const int tid  = threadIdx.x;
    const int lane = tid & 63, wave = tid >> 6;
    const int wm = wave >> 1, wn = wave & 1;
    const int l15 = lane & 15, quad = lane >> 4;
    const int row0 = blockIdx.x * 128, col0 = blockIdx.y * 128;

    f32x4 acc[4][4];
    for (int i = 0; i < 4; ++i)
        for (int j = 0; j < 4; ++j) acc[i][j] = f32x4{0.f, 0.f, 0.f, 0.f};

    for (int kt = 0; kt < ID_ / 32; ++kt) {
        const int k0 = kt * 32;
        for (int L = tid; L < 512; L += 256) {
            const int r = L >> 2, s = L & 3;
            *reinterpret_cast<i32x4*>(&As[r * 40 + s * 8]) =
                *reinterpret_cast<const i32x4*>(xb + (size_t)(row0 + r) * ID_ + k0 + s * 8);
            *reinterpret_cast<i32x4*>(&Bs[r * 40 + s * 8]) =
                *reinterpret_cast<const i32x4*>(wiT + (size_t)(col0 + r) * ID_ + k0 + s * 8);
        }
        __syncthreads();
        bf16x8 af[4], bfv[4];
        for (int mt = 0; mt < 4; ++mt)
            af[mt] = *reinterpret_cast<const bf16x8*>(
                &As[(wm * 64 + mt * 16 + l15) * 40 + quad * 8]);
        for (int nt = 0; nt < 4; ++nt)
            bfv[nt] = *reinterpret_cast<const bf16x8*>(
                &Bs[(wn * 64 + nt * 16 + l15) * 40 + quad * 8]);
        for (int mt = 0; mt < 4; ++mt)
            for (int nt = 0; nt < 4; ++nt)
                acc[mt][nt] = __builtin_amdgcn_mfma_f32_16x16x32_bf16(
                    af[mt], bfv[nt], acc[mt][nt], 0, 0, 0);
        __syncthreads();
    }
    // epilogue: +(bi+bh), natural-layout coalesced stores
    for (int mt = 0; mt < 4; ++mt) {
        for (int nt = 0; nt < 4; ++nt) {
            const int cg = col0 + wn * 64 + nt * 16 + l15;
            const float bias = bi[cg] + bh[cg];
            for (int r = 0; r < 4; ++r) {
                const int rg = row0 + wm * 64 + mt * 16 + quad * 4 + r;
                gates3[(size_t)rg * NG_ + cg] =
                    __float2bfloat16(acc[mt][nt][r] + bias);
            }
        }
    }
}

// ------------------------------------------------- persistent LSTM steps ----
// r13 structure verbatim. 256 threads = 4 waves; wave w owns batches
// [w*16, w*16+16); thread owns (batch b = w*16+l15, units quad*4..+3).
// LDS Wh tile: 64 m-rows (4 gates x 16 units) x 1024 k, 128 KB.
// Element layout: kk*2048 + sel*512 + lane*8 (sel = gate) -- conflict-free.
__global__ __launch_bounds__(256, 1) void lstm_persistent_kernel(
    const bf16* __restrict__ gates3, const bf16* __restrict__ whT,
    bf16* __restrict__ hbuf, float* __restrict__ out, int* __restrict__ flags) {
    __shared__ __align__(16) bf16 whs[32 * 4 * 64 * 8];   // 128 KB
    const int tid  = threadIdx.x;
    const int lane = tid & 63, w = tid >> 6;
    const int l15 = lane & 15, quad = lane >> 4;
    const int blk = blockIdx.x;                 // units [blk*16, blk*16+16)

    // ---- stage Wh A-tile into LDS (once), linear 16B writes ----
    for (int c = tid; c < 8192; c += 256) {
        const int kk = c >> 8, sel = (c >> 6) & 3, ln = c & 63;
        const size_t wrow = (size_t)(sel * HD_ + blk * UPB + (ln & 15));
        const int col = (ln >> 4) * 8 + kk * 32;
        *reinterpret_cast<i32x4*>(whs + (size_t)c * 8) =
            *reinterpret_cast<const i32x4*>(whT + wrow * HD_ + col);
    }
    __syncthreads();

    const bf16* wb = whs + (size_t)lane * 8;    // + kk*2048 + sel*512

    const int b = w * 16 + l15;                 // batch row
    float cs[4] = {0.f, 0.f, 0.f, 0.f};

    // block flags[0..63]: wave 0 lane i polls flags[i]; waves 1-3 released
    // by s_barrier. Producer: drain -> s_barrier -> tid0 stores flags[blk].
    const volatile int* pf = (const volatile int*)(flags + lane);

    // gx: natural layout -> 4 x 8B loads (one per gate), dbuffered one
    // step ahead (issued after the publish, never on the critical path).
    const bf16* gxb0 = gates3 + (size_t)b * T_ * NG_ + blk * UPB + quad * 4;
    bf16x4v gF_n = *reinterpret_cast<const bf16x4v*>(gxb0);
    bf16x4v gI_n = *reinterpret_cast<const bf16x4v*>(gxb0 + 1024);
    bf16x4v gA_n = *reinterpret_cast<const bf16x4v*>(gxb0 + 2048);
    bf16x4v gO_n = *reinterpret_cast<const bf16x4v*>(gxb0 + 3072);

    for (int t = 0; t < T_; ++t) {
        const bf16* hin  = hbuf + (size_t)(t & 1) * (B_ * HD_);
        bf16*       hout = hbuf + (size_t)((t + 1) & 1) * (B_ * HD_);
        const bf16x4v gF = gF_n, gI = gI_n, gA = gA_n, gO = gO_n;

        if (t > 0) {
            if (w == 0) {
                while (*pf < t) __builtin_amdgcn_s_sleep(2);
            }
            asm volatile("s_barrier" ::: "memory");
        }

        f32x4 aFe{0.f,0.f,0.f,0.f}, aFo{0.f,0.f,0.f,0.f};
        f32x4 aIe{0.f,0.f,0.f,0.f}, aIo{0.f,0.f,0.f,0.f};
        f32x4 aAe{0.f,0.f,0.f,0.f}, aAo{0.f,0.f,0.f,0.f};
        f32x4 aOe{0.f,0.f,0.f,0.f}, aOo{0.f,0.f,0.f,0.f};

        // ---- h B-frags: ping-pong groups of 8, counted vmcnt(8) ----
        const bf16* hb_base = hin + (size_t)b * HD_ + quad * 8;
        i32x4 hbA[8], hbB[8];

        auto consume8 = [&](const i32x4* hbg, const int kkb) {
#pragma unroll
            for (int i = 0; i < 8; i += 2) {
                const int kk = kkb + i;
                const bf16* f0 = wb + (size_t)kk * 2048;
                const bf16* f1 = f0 + 2048;
                const bf16x8 he = as_bf16x8(hbg[i]);
                const bf16x8 ho = as_bf16x8(hbg[i + 1]);
                aFe = __builtin_amdgcn_mfma_f32_16x16x32_bf16(
                    *reinterpret_cast<const bf16x8*>(f0),        he, aFe, 0, 0, 0);
                aIe = __builtin_amdgcn_mfma_f32_16x16x32_bf16(
                    *reinterpret_cast<const bf16x8*>(f0 + 512),  he, aIe, 0, 0, 0);
                aAe = __builtin_amdgcn_mfma_f32_16x16x32_bf16(
                    *reinterpret_cast<const bf16x8*>(f0 + 1024), he, aAe, 0, 0, 0);
                aOe = __builtin_amdgcn_mfma_f32_16x16x32_bf16(
                    *reinterpret_cast<const bf16x8*>(f0 + 1536), he, aOe, 0, 0, 0);
                aFo = __builtin_amdgcn_mfma_f32_16x16x32_bf16(
                    *reinterpret_cast<const bf16x8*>(f1),        ho, aFo, 0, 0, 0);
                aIo = __builtin_amdgcn_mfma_f32_16x16x32_bf16(
                    *reinterpret_cast<const bf16x8*>(f1 + 512),  ho, aIo, 0, 0, 0);
                aAo = __builtin_amdgcn_mfma_f32_16x16x32_bf16(
                    *reinterpret_cast<const bf16x8*>(f1 + 1024), ho, aAo, 0, 0, 0);
                aOo = __builtin_amdgcn_mfma_f32_16x16x32_bf16(
                    *reinterpret_cast<const bf16x8*>(f1 + 1536), ho, aOo, 0, 0, 0);
            }
        };

        issue8(hbA, hb_base);             // kk  0..7
        issue8(hbB, hb_base + 8 * 32);    // kk  8..15
        asm volatile("s_waitcnt vmcnt(8)" ::: "memory");
        __builtin_amdgcn_sched_barrier(0);
        consume8(hbA, 0);
        issue8(hbA, hb_base + 16 * 32);   // kk 16..23
        asm volatile("s_waitcnt vmcnt(8)" ::: "memory");
        __builtin_amdgcn_sched_barrier(0);
        consume8(hbB, 8);
        issue8(hbB, hb_base + 24 * 32);   // kk 24..31
        asm volatile("s_waitcnt vmcnt(8)" ::: "memory");
        __builtin_amdgcn_sched_barrier(0);
        consume8(hbA, 16);
        asm volatile("s_waitcnt vmcnt(0)" ::: "memory");
        __builtin_amdgcn_sched_barrier(0);
        consume8(hbB, 24);

        // ---- activations: all 4 gates local per (unit, batch) ----
        const f32x4 accF = aFe + aFo;
        const f32x4 accI = aIe + aIo;
        const f32x4 accA = aAe + aAo;
        const f32x4 accO = aOe + aOo;
        float hs[4];
#pragma unroll
        for (int r = 0; r < 4; ++r) {
            const float fv = sigmoid_fast(accF[r] + (float)gF[r]);
            const float iv = sigmoid_fast(accI[r] + (float)gI[r]);
            const float av = tanh_fast   (accA[r] + (float)gA[r]);
            const float ov = sigmoid_fast(accO[r] + (float)gO[r]);
            cs[r] = fv * cs[r] + iv * av;
            hs[r] = ov * tanh_fast(cs[r]);
        }

        const int hidx = b * HD_ + blk * UPB + quad * 4;
        // out stores FIRST: acks drain inside the publish vmcnt(0),
        // overlapped with the h MALL ack (r12 lesson).
        *reinterpret_cast<float4*>(
            out + ((size_t)b * T_ + t) * HD_ + blk * UPB + quad * 4) =
            make_float4(hs[0], hs[1], hs[2], hs[3]);
        if (t == T_ - 1) {
            *reinterpret_cast<float4*>(out + (size_t)M1_ * HD_ + hidx) =
                make_float4(hs[0], hs[1], hs[2], hs[3]);
            *reinterpret_cast<float4*>(
                out + (size_t)M1_ * HD_ + B_ * HD_ + hidx) =
                make_float4(cs[0], cs[1], cs[2], cs[3]);
        }
        if (t < T_ - 1) {
            const unsigned long long hp =
                (unsigned long long)bf16_bits(hs[0]) |
                ((unsigned long long)bf16_bits(hs[1]) << 16) |
                ((unsigned long long)bf16_bits(hs[2]) << 32) |
                ((unsigned long long)bf16_bits(hs[3]) << 48);
            *reinterpret_cast<volatile unsigned long long*>(hout + hidx) = hp;
            // drain own h (MALL) + out acks, block barrier, ONE flag store.
            __asm__ __volatile__("s_waitcnt vmcnt(0)" ::: "memory");
            asm volatile("s_barrier" ::: "memory");
            if (tid == 0)
                *reinterpret_cast<volatile int*>(flags + blk) = t + 1;
            __asm__ __volatile__("" ::: "memory");
            // prefetch next step's gx: a full step of latency to hide.
            const bf16* gxp = gates3 +
                ((size_t)b * T_ + (t + 1)) * NG_ + blk * UPB + quad * 4;
            gF_n = *reinterpret_cast<const bf16x4v*>(gxp);
            gI_n = *reinterpret_cast<const bf16x4v*>(gxp + 1024);
            gA_n = *reinterpret_cast<const bf16x4v*>(gxp + 2048);
            gO_n = *reinterpret_cast<const bf16x4v*>(gxp + 3072);
        }
    }
}

// -------------------------------------------------------------- launcher ----
extern "C" void kernel_launch(void* const* d_in, const int* in_sizes, int n_in,
                              void* d_out, int out_size, void* d_ws, size_t ws_size,
                              hipStream_t stream) {
    const float* x  = (const float*)d_in[0];
    const float* Wi = (const float*)d_in[1];
    const float* bi = (const float*)d_in[2];
    const float* Wh = (const float*)d_in[3];
    const float* bh = (const float*)d_in[4];
    float* out = (float*)d_out;

    char* ws = (char*)d_ws;
    size_t off = 0;
    bf16* xb     = (bf16*)(ws + off); off += (size_t)M1_ * ID_ * 2;       // 16 MB
    bf16* wiT    = (bf16*)(ws + off); off += (size_t)NG_ * ID_ * 2;       // 4 MB
    bf16* whT    = (bf16*)(ws + off); off += (size_t)NG_ * HD_ * 2;       // 8 MB
    bf16* gates3 = (bf16*)(ws + off); off += (size_t)T_ * B_ * NG_ * 2;   // 128 MB
    bf16* hbuf   = (bf16*)(ws + off); off += (size_t)2 * B_ * HD_ * 2;    // 256 KB
    int* flags   = (int*)(ws + off);  off += (size_t)NBLK * 4 * 16 * 4;   // 16 KB

    prep_kernel<<<8192, 256, 0, stream>>>(x, xb, hbuf, flags);
    transpose_kernel<<<1536, 256, 0, stream>>>(Wi, Wh, wiT, whT);
    gates_gemm_kernel<<<dim3(128, 32), 256, 0, stream>>>(xb, wiT, bi, bh, gates3);

    lstm_persistent_kernel<<<dim3(NBLK), dim3(256), 0, stream>>>(
        gates3, whT, hbuf, out, flags);
}